// Round 3
// baseline (330.216 us; speedup 1.0000x reference)
//
#include <hip/hip_runtime.h>

#define NB 8
#define NN 20000
#define FI 128
#define FO 128
#define NE 320000
#define ROWS (NB * NN)        // 160000 flattened (b,n) rows
#define LRALPHA 0.2f

typedef short bf16x8 __attribute__((ext_vector_type(8)));
typedef float f32x4 __attribute__((ext_vector_type(4)));

static __device__ __forceinline__ float b2f(unsigned short u) {
  return __uint_as_float(((unsigned int)u) << 16);
}
static __device__ __forceinline__ unsigned short f2b(float f) {
  unsigned int u = __float_as_uint(f);
  return (unsigned short)((u + 0x7FFFu + ((u >> 16) & 1u)) >> 16);  // RNE
}

// ---- W transpose: W[k][o] fp32 -> Wb[o][k] bf16 (32 KB, stays L1/L2-hot) --
__global__ __launch_bounds__(256) void wt_kernel(const float* __restrict__ W,
                                                 unsigned short* __restrict__ Wb) {
  int idx = blockIdx.x * 256 + threadIdx.x;  // 0..16383
  int k = idx >> 7, o = idx & 127;
  Wb[o * 128 + k] = f2b(W[idx]);
}

// ---- GEMM: LDS-free streaming MFMA; h bf16 out + fused g1/g2 --------------
// wave = 16 rows; block = 4 waves = 64 rows; 2500 blocks.
__global__ __launch_bounds__(256) void gemm_kernel(
    const float* __restrict__ x, const unsigned short* __restrict__ Wb,
    const float* __restrict__ a,
    unsigned short* __restrict__ hb,
    float* __restrict__ g1, float* __restrict__ g2) {
  const int tid = threadIdx.x;
  const int wv = tid >> 6;
  const int lane = tid & 63;
  const int m = lane & 15;
  const int quad = lane >> 4;
  const size_t row0 = (size_t)blockIdx.x * 64 + wv * 16;  // wave's first row

  // A-fragments: x[row0+m][k0*32 + quad*8 .. +8] fp32 -> bf16 in-reg
  const float* xr = x + (row0 + m) * 128;
  bf16x8 afr[4];
#pragma unroll
  for (int k0 = 0; k0 < 4; ++k0) {
    const float4* xp = (const float4*)(xr + k0 * 32 + quad * 8);
    float4 v0 = xp[0];
    float4 v1 = xp[1];
    union { bf16x8 v; unsigned short u[8]; } af;
    af.u[0] = f2b(v0.x); af.u[1] = f2b(v0.y);
    af.u[2] = f2b(v0.z); af.u[3] = f2b(v0.w);
    af.u[4] = f2b(v1.x); af.u[5] = f2b(v1.y);
    af.u[6] = f2b(v1.z); af.u[7] = f2b(v1.w);
    afr[k0] = af.v;
  }

  f32x4 acc[8] = {};
#pragma unroll
  for (int k0 = 0; k0 < 4; ++k0) {
#pragma unroll
    for (int c = 0; c < 8; ++c) {
      bf16x8 bf = *(const bf16x8*)&Wb[(c * 16 + m) * 128 + k0 * 32 + quad * 8];
      acc[c] = __builtin_amdgcn_mfma_f32_16x16x32_bf16(afr[k0], bf, acc[c], 0, 0, 0);
    }
  }

  // C/D layout: col = lane&15 (within c-tile), row = quad*4 + r
  unsigned short* hp = hb + row0 * 128;
#pragma unroll
  for (int c = 0; c < 8; ++c)
#pragma unroll
    for (int r = 0; r < 4; ++r)
      hp[(quad * 4 + r) * 128 + c * 16 + m] = f2b(acc[c][r]);

  // fused g1/g2: per-row dot with a1/a2 from fp32 accumulators
  float a1v[8], a2v[8];
#pragma unroll
  for (int c = 0; c < 8; ++c) {
    a1v[c] = a[c * 16 + m];
    a2v[c] = a[128 + c * 16 + m];
  }
  float p1[4] = {}, p2[4] = {};
#pragma unroll
  for (int c = 0; c < 8; ++c)
#pragma unroll
    for (int r = 0; r < 4; ++r) {
      p1[r] = fmaf(acc[c][r], a1v[c], p1[r]);
      p2[r] = fmaf(acc[c][r], a2v[c], p2[r]);
    }
#pragma unroll
  for (int off = 1; off < 16; off <<= 1)
#pragma unroll
    for (int r = 0; r < 4; ++r) {
      p1[r] += __shfl_xor(p1[r], off, 64);
      p2[r] += __shfl_xor(p2[r], off, 64);
    }
  if (m == 0) {
    size_t rbase = row0 + quad * 4;
#pragma unroll
    for (int r = 0; r < 4; ++r) {
      g1[rbase + r] = p1[r];
      g2[rbase + r] = p2[r];
    }
  }
}

// ---------------- CSR build: histogram -> scan -> scatter -------------------
__global__ __launch_bounds__(256) void hist_kernel(const int* __restrict__ src,
                                                   int* __restrict__ counts) {
  int e = blockIdx.x * 256 + threadIdx.x;
  if (e < NE) atomicAdd(&counts[src[e]], 1);
}

__global__ __launch_bounds__(1024) void scan_kernel(
    const int* __restrict__ counts, int* __restrict__ offsets,
    int* __restrict__ cursor) {
  __shared__ int sc[NN];      // 80 KB
  __shared__ int sums[1024];
  const int t = threadIdx.x;
  for (int idx = t; idx < NN; idx += 1024) sc[idx] = counts[idx];  // coalesced
  __syncthreads();
  int local[20];
  int base = t * 20;
  int s = 0;
#pragma unroll
  for (int c = 0; c < 20; ++c) {
    int idx = base + c;
    int v = (idx < NN) ? sc[idx] : 0;
    local[c] = s;
    s += v;
  }
  sums[t] = s;
  __syncthreads();
  for (int off = 1; off < 1024; off <<= 1) {
    int u = 0;
    if (t >= off) u = sums[t - off];
    __syncthreads();
    sums[t] += u;
    __syncthreads();
  }
  int prefix = sums[t] - s;  // exclusive over threads
#pragma unroll
  for (int c = 0; c < 20; ++c) {
    int idx = base + c;
    if (idx < NN) {
      int o = prefix + local[c];
      offsets[idx] = o;
      cursor[idx] = o;
    }
  }
  if (t == 0) offsets[NN] = NE;
}

// scatter: store dst directly at CSR position (kills one indirection level
// in gather and makes gather's index loads coalesced)
__global__ __launch_bounds__(256) void scatter_kernel(
    const int* __restrict__ src, const int* __restrict__ dst,
    int* __restrict__ cursor, int* __restrict__ csr_dst) {
  int e = blockIdx.x * 256 + threadIdx.x;
  if (e < NE) {
    int s = src[e];
    int d = dst[e];
    int pos = atomicAdd(&cursor[s], 1);
    csr_dst[pos] = d;
  }
}

// ---------------- gather: per (node i, batch b) segment reduce --------------
// Lane-parallel weight compute + batched (8-deep) h-row load issuance.
__global__ __launch_bounds__(64) void gather_kernel(
    const unsigned short* __restrict__ hb, const float* __restrict__ g1,
    const float* __restrict__ g2, const int* __restrict__ offsets,
    const int* __restrict__ csr_dst, float* __restrict__ out) {
  const int i = blockIdx.x;
  const int b = blockIdx.y;
  const int lane = threadIdx.x;
  const int beg = offsets[i];
  const int deg = offsets[i + 1] - beg;
  const float g1i = g1[(size_t)b * NN + i];
  const float* g2b = g2 + (size_t)b * NN;
  const unsigned short* hbb = hb + (size_t)b * NN * 128;

  float accx = 0.f, accy = 0.f, rs = 0.f;
  for (int c0 = 0; c0 < deg; c0 += 64) {
    const int cnt = min(64, deg - c0);
    // lane-parallel: lane e computes weight for edge beg+c0+e (coalesced idx)
    int myd = 0;
    float w = 0.f;
    if (lane < cnt) {
      myd = csr_dst[beg + c0 + lane];
      float s = g1i + g2b[myd];
      float sc = fmaxf(s, LRALPHA * s);
      w = __expf(-sc);
    }
    rs += w;
    // accumulate h rows: broadcast (d,w) from lane j, 8 loads in flight
    const int cr = (cnt + 7) & ~7;  // zero-weight padding kills extras
    for (int e = 0; e < cr; e += 8) {
      ushort2 hv[8];
      float we[8];
#pragma unroll
      for (int j = 0; j < 8; ++j) {
        int d = __shfl(myd, e + j, 64);
        we[j] = __shfl(w, e + j, 64);
        hv[j] = *(const ushort2*)&hbb[(size_t)d * 128 + 2 * lane];
      }
#pragma unroll
      for (int j = 0; j < 8; ++j) {
        accx = fmaf(we[j], b2f(hv[j].x), accx);
        accy = fmaf(we[j], b2f(hv[j].y), accy);
      }
    }
  }
#pragma unroll
  for (int off = 32; off >= 1; off >>= 1) rs += __shfl_xor(rs, off, 64);
  float inv = 1.f / rs;
  float ox = accx * inv, oy = accy * inv;
  ox = ox > 0.f ? ox : expm1f(ox);      // elu (alpha=1)
  oy = oy > 0.f ? oy : expm1f(oy);
  float2* op = (float2*)(out + ((size_t)b * NN + i) * 128);
  op[lane] = make_float2(ox, oy);
}

extern "C" void kernel_launch(void* const* d_in, const int* in_sizes, int n_in,
                              void* d_out, int out_size, void* d_ws, size_t ws_size,
                              hipStream_t stream) {
  const float* x = (const float*)d_in[0];
  const float* W = (const float*)d_in[1];
  const float* a = (const float*)d_in[2];
  const int* edge = (const int*)d_in[3];
  const int* src = edge;
  const int* dst = edge + NE;
  float* out = (float*)d_out;

  // workspace layout (~43.7 MB)
  char* p = (char*)d_ws;
  unsigned short* hb = (unsigned short*)p;  p += (size_t)ROWS * 128 * 2;  // 40.96 MB
  float* g1 = (float*)p;                    p += (size_t)ROWS * 4;
  float* g2 = (float*)p;                    p += (size_t)ROWS * 4;
  int* counts = (int*)p;                    p += (size_t)NN * 4;
  int* offsets = (int*)p;                   p += (size_t)(NN + 1) * 4;
  int* cursor = (int*)p;                    p += (size_t)NN * 4;
  int* csr_dst = (int*)p;                   p += (size_t)NE * 4;
  unsigned short* Wb = (unsigned short*)p;  p += (size_t)FI * FO * 2;

  hipMemsetAsync(counts, 0, NN * sizeof(int), stream);
  wt_kernel<<<64, 256, 0, stream>>>(W, Wb);
  gemm_kernel<<<ROWS / 64, 256, 0, stream>>>(x, Wb, a, hb, g1, g2);
  hist_kernel<<<(NE + 255) / 256, 256, 0, stream>>>(src, counts);
  scan_kernel<<<1, 1024, 0, stream>>>(counts, offsets, cursor);
  scatter_kernel<<<(NE + 255) / 256, 256, 0, stream>>>(src, dst, cursor, csr_dst);
  dim3 ggrid(NN, NB);
  gather_kernel<<<ggrid, 64, 0, stream>>>(hb, g1, g2, offsets, csr_dst, out);
}

// Round 4
// 293.579 us; speedup vs baseline: 1.1248x; 1.1248x over previous
//
#include <hip/hip_runtime.h>

#define NB 8
#define NN 20000
#define FI 128
#define FO 128
#define NE 320000
#define ROWS (NB * NN)        // 160000 flattened (b,n) rows
#define LRALPHA 0.2f

typedef short bf16x8 __attribute__((ext_vector_type(8)));
typedef float f32x4 __attribute__((ext_vector_type(4)));

static __device__ __forceinline__ float b2f(unsigned short u) {
  return __uint_as_float(((unsigned int)u) << 16);
}
static __device__ __forceinline__ unsigned short f2b(float f) {
  unsigned int u = __float_as_uint(f);
  return (unsigned short)((u + 0x7FFFu + ((u >> 16) & 1u)) >> 16);  // RNE
}

// ---- W transpose: W[k][o] fp32 -> Wb[o][k] bf16; also zero counts ---------
__global__ __launch_bounds__(256) void wt_kernel(const float* __restrict__ W,
                                                 unsigned short* __restrict__ Wb,
                                                 int* __restrict__ counts) {
  int idx = blockIdx.x * 256 + threadIdx.x;  // 80 blocks -> 20480 threads
  if (idx < FI * FO) {
    int k = idx >> 7, o = idx & 127;
    Wb[o * 128 + k] = f2b(W[idx]);
  }
  if (idx < NN) counts[idx] = 0;
}

// ---- GEMM: W in padded LDS (cheap staging), x streamed; fused g1/g2 -------
#define LDW 136  // padded LDS stride: m-stride 272B -> 2-way bank alias (free)

__global__ __launch_bounds__(256) void gemm_kernel(
    const float* __restrict__ x, const unsigned short* __restrict__ Wb,
    const float* __restrict__ a,
    unsigned short* __restrict__ hb,
    float* __restrict__ g1, float* __restrict__ g2) {
  __shared__ __align__(16) unsigned short Ws[128 * LDW];  // 34.8 KB
  const int tid = threadIdx.x;

  // stage Wb (already bf16, [o][k]) into padded LDS: coalesced 16B chunks
  {
    const bf16x8* wsrc = (const bf16x8*)Wb;
#pragma unroll
    for (int it = 0; it < 8; ++it) {
      int c = tid + it * 256;          // 16B chunk id, 0..2047
      int o = c >> 4, seg = c & 15;
      *(bf16x8*)&Ws[o * LDW + seg * 8] = wsrc[c];
    }
  }

  const int wv = tid >> 6;
  const int lane = tid & 63;
  const int m = lane & 15;
  const int quad = lane >> 4;
  const size_t row0 = (size_t)blockIdx.x * 64 + wv * 16;  // wave's first row

  // A-fragments: x[row0+m][k0*32 + quad*8 .. +8] fp32 -> bf16 in-reg
  const float* xr = x + (row0 + m) * 128;
  bf16x8 afr[4];
#pragma unroll
  for (int k0 = 0; k0 < 4; ++k0) {
    const float4* xp = (const float4*)(xr + k0 * 32 + quad * 8);
    float4 v0 = xp[0];
    float4 v1 = xp[1];
    union { bf16x8 v; unsigned short u[8]; } af;
    af.u[0] = f2b(v0.x); af.u[1] = f2b(v0.y);
    af.u[2] = f2b(v0.z); af.u[3] = f2b(v0.w);
    af.u[4] = f2b(v1.x); af.u[5] = f2b(v1.y);
    af.u[6] = f2b(v1.z); af.u[7] = f2b(v1.w);
    afr[k0] = af.v;
  }
  __syncthreads();

  f32x4 acc[8] = {};
#pragma unroll
  for (int k0 = 0; k0 < 4; ++k0) {
#pragma unroll
    for (int c = 0; c < 8; ++c) {
      bf16x8 bf = *(const bf16x8*)&Ws[(c * 16 + m) * LDW + k0 * 32 + quad * 8];
      acc[c] = __builtin_amdgcn_mfma_f32_16x16x32_bf16(afr[k0], bf, acc[c], 0, 0, 0);
    }
  }

  // C/D layout: col = lane&15 (within c-tile), row = quad*4 + r
  unsigned short* hp = hb + row0 * 128;
#pragma unroll
  for (int c = 0; c < 8; ++c)
#pragma unroll
    for (int r = 0; r < 4; ++r)
      hp[(quad * 4 + r) * 128 + c * 16 + m] = f2b(acc[c][r]);

  // fused g1/g2: per-row dot with a1/a2 from fp32 accumulators
  float a1v[8], a2v[8];
#pragma unroll
  for (int c = 0; c < 8; ++c) {
    a1v[c] = a[c * 16 + m];
    a2v[c] = a[128 + c * 16 + m];
  }
  float p1[4] = {}, p2[4] = {};
#pragma unroll
  for (int c = 0; c < 8; ++c)
#pragma unroll
    for (int r = 0; r < 4; ++r) {
      p1[r] = fmaf(acc[c][r], a1v[c], p1[r]);
      p2[r] = fmaf(acc[c][r], a2v[c], p2[r]);
    }
#pragma unroll
  for (int off = 1; off < 16; off <<= 1)
#pragma unroll
    for (int r = 0; r < 4; ++r) {
      p1[r] += __shfl_xor(p1[r], off, 64);
      p2[r] += __shfl_xor(p2[r], off, 64);
    }
  if (m == 0) {
    size_t rbase = row0 + quad * 4;
#pragma unroll
    for (int r = 0; r < 4; ++r) {
      g1[rbase + r] = p1[r];
      g2[rbase + r] = p2[r];
    }
  }
}

// ---------------- CSR build: histogram -> scan -> scatter -------------------
__global__ __launch_bounds__(256) void hist_kernel(const int* __restrict__ src,
                                                   int* __restrict__ counts) {
  int e = blockIdx.x * 256 + threadIdx.x;
  if (e < NE) atomicAdd(&counts[src[e]], 1);
}

__global__ __launch_bounds__(1024) void scan_kernel(
    const int* __restrict__ counts, int* __restrict__ offsets,
    int* __restrict__ cursor) {
  __shared__ int sc[NN];      // 80 KB
  __shared__ int sums[1024];
  const int t = threadIdx.x;
  for (int idx = t; idx < NN; idx += 1024) sc[idx] = counts[idx];  // coalesced
  __syncthreads();
  int local[20];
  int base = t * 20;
  int s = 0;
#pragma unroll
  for (int c = 0; c < 20; ++c) {
    int idx = base + c;
    int v = (idx < NN) ? sc[idx] : 0;
    local[c] = s;
    s += v;
  }
  sums[t] = s;
  __syncthreads();
  for (int off = 1; off < 1024; off <<= 1) {
    int u = 0;
    if (t >= off) u = sums[t - off];
    __syncthreads();
    sums[t] += u;
    __syncthreads();
  }
  int prefix = sums[t] - s;  // exclusive over threads
#pragma unroll
  for (int c = 0; c < 20; ++c) {
    int idx = base + c;
    if (idx < NN) {
      int o = prefix + local[c];
      offsets[idx] = o;
      cursor[idx] = o;
    }
  }
  if (t == 0) offsets[NN] = NE;
}

// scatter: store dst directly at CSR position
__global__ __launch_bounds__(256) void scatter_kernel(
    const int* __restrict__ src, const int* __restrict__ dst,
    int* __restrict__ cursor, int* __restrict__ csr_dst) {
  int e = blockIdx.x * 256 + threadIdx.x;
  if (e < NE) {
    int s = src[e];
    int d = dst[e];
    int pos = atomicAdd(&cursor[s], 1);
    csr_dst[pos] = d;
  }
}

// ---------------- gather: per (node i, batch b) segment reduce --------------
// Lane-parallel weights; h-rows loaded 16-lanes-per-row (4 edges per load).
__global__ __launch_bounds__(64) void gather_kernel(
    const unsigned short* __restrict__ hb, const float* __restrict__ g1,
    const float* __restrict__ g2, const int* __restrict__ offsets,
    const int* __restrict__ csr_dst, float* __restrict__ out) {
  const int i = blockIdx.x;
  const int b = blockIdx.y;
  const int lane = threadIdx.x;
  const int quad = lane >> 4;
  const int beg = offsets[i];
  const int deg = offsets[i + 1] - beg;
  const float g1i = g1[(size_t)b * NN + i];
  const float* g2b = g2 + (size_t)b * NN;
  // lane's 16B slice within any h-row of batch b
  const char* hbase = (const char*)(hb + (size_t)b * NN * 128) + (lane & 15) * 16;

  float acc[8] = {};
  float rs = 0.f;
  for (int c0 = 0; c0 < deg; c0 += 64) {
    const int cnt = min(64, deg - c0);
    // lane-parallel: lane e computes weight for edge beg+c0+e (coalesced idx)
    int myd = 0;
    float w = 0.f;
    if (lane < cnt) {
      myd = csr_dst[beg + c0 + lane];
      float s = g1i + g2b[myd];
      float sc = fmaxf(s, LRALPHA * s);
      w = __expf(-sc);
    }
    rs += w;
    // 4 edges per load: quad q takes edge e+j*4+q; zero-weight padding
    const int cr = (cnt + 15) & ~15;
    for (int e = 0; e < cr; e += 16) {
      bf16x8 hv[4];
      float we[4];
#pragma unroll
      for (int j = 0; j < 4; ++j) {
        int idx = e + j * 4 + quad;
        int d = __shfl(myd, idx, 64);
        we[j] = __shfl(w, idx, 64);
        hv[j] = *(const bf16x8*)(hbase + (d << 8));
      }
#pragma unroll
      for (int j = 0; j < 4; ++j) {
        union { bf16x8 v; unsigned short u[8]; } hu;
        hu.v = hv[j];
#pragma unroll
        for (int k = 0; k < 8; ++k)
          acc[k] = fmaf(we[j], b2f(hu.u[k]), acc[k]);
      }
    }
  }
  // reduce partial edge-sums across quads (edges distributed mod 4)
#pragma unroll
  for (int k = 0; k < 8; ++k) {
    acc[k] += __shfl_xor(acc[k], 16, 64);
    acc[k] += __shfl_xor(acc[k], 32, 64);
  }
#pragma unroll
  for (int off = 32; off >= 1; off >>= 1) rs += __shfl_xor(rs, off, 64);

  if (lane < 16) {
    float inv = 1.f / rs;
    float o[8];
#pragma unroll
    for (int k = 0; k < 8; ++k) {
      float v = acc[k] * inv;
      o[k] = v > 0.f ? v : expm1f(v);   // elu (alpha=1)
    }
    float4* op = (float4*)(out + ((size_t)b * NN + i) * 128 + lane * 8);
    op[0] = make_float4(o[0], o[1], o[2], o[3]);
    op[1] = make_float4(o[4], o[5], o[6], o[7]);
  }
}

extern "C" void kernel_launch(void* const* d_in, const int* in_sizes, int n_in,
                              void* d_out, int out_size, void* d_ws, size_t ws_size,
                              hipStream_t stream) {
  const float* x = (const float*)d_in[0];
  const float* W = (const float*)d_in[1];
  const float* a = (const float*)d_in[2];
  const int* edge = (const int*)d_in[3];
  const int* src = edge;
  const int* dst = edge + NE;
  float* out = (float*)d_out;

  // workspace layout (~43.7 MB)
  char* p = (char*)d_ws;
  unsigned short* hb = (unsigned short*)p;  p += (size_t)ROWS * 128 * 2;  // 40.96 MB
  float* g1 = (float*)p;                    p += (size_t)ROWS * 4;
  float* g2 = (float*)p;                    p += (size_t)ROWS * 4;
  int* counts = (int*)p;                    p += (size_t)NN * 4;
  int* offsets = (int*)p;                   p += (size_t)(NN + 1) * 4;
  int* cursor = (int*)p;                    p += (size_t)NN * 4;
  int* csr_dst = (int*)p;                   p += (size_t)NE * 4;
  unsigned short* Wb = (unsigned short*)p;  p += (size_t)FI * FO * 2;

  wt_kernel<<<80, 256, 0, stream>>>(W, Wb, counts);  // also zeroes counts
  gemm_kernel<<<ROWS / 64, 256, 0, stream>>>(x, Wb, a, hb, g1, g2);
  hist_kernel<<<(NE + 255) / 256, 256, 0, stream>>>(src, counts);
  scan_kernel<<<1, 1024, 0, stream>>>(counts, offsets, cursor);
  scatter_kernel<<<(NE + 255) / 256, 256, 0, stream>>>(src, dst, cursor, csr_dst);
  dim3 ggrid(NN, NB);
  gather_kernel<<<ggrid, 64, 0, stream>>>(hb, g1, g2, offsets, csr_dst, out);
}